// Round 2
// baseline (126.492 us; speedup 1.0000x reference)
//
#include <hip/hip_runtime.h>
#include <hip/hip_bf16.h>

// Problem constants (from reference): B=4,S=2048,K=2,C=32,D=128,P=128
#define P_  128
#define C_  32
#define D_  128
#define BS_ 8192          // B*S rows
#define PD_ (P_*D_)       // 16384 floats = 64 KB

// Kernel 1: per-block partial means tables in LDS, written non-atomically to ws.
// One wave handles one (b,s) row: lanes 0..63 hold keys[r, i=lane>>5, c=lane&31].
__global__ __launch_bounds__(256) void scatter_partials(
    const int* __restrict__ idx, const float* __restrict__ keys,
    const float* __restrict__ values, float* __restrict__ partials,
    int rowsPerBlk)
{
    __shared__ float lmeans[PD_];
    const int tid  = threadIdx.x;
    for (int i = tid; i < PD_; i += 256) lmeans[i] = 0.f;
    __syncthreads();

    const int lane = tid & 63;
    const int wave = tid >> 6;
    const int r0 = blockIdx.x * rowsPerBlk;
    int r1 = r0 + rowsPerBlk; if (r1 > BS_) r1 = BS_;

    for (int r = r0 + wave; r < r1; r += 4) {
        // key element for this lane (covers both K entries: K*C = 64)
        float s = keys[(size_t)r * 64 + lane];
        // xor-reduce within each 32-lane half -> per-half sums everywhere
        s += __shfl_xor(s, 16);
        s += __shfl_xor(s, 8);
        s += __shfl_xor(s, 4);
        s += __shfl_xor(s, 2);
        s += __shfl_xor(s, 1);
        const float ks0 = __shfl(s, 0)  * (1.f / 32.f);  // mean over C for i=0
        const float ks1 = __shfl(s, 32) * (1.f / 32.f);  // mean over C for i=1
        const int i0 = idx[r * 2 + 0];
        const int i1 = idx[r * 2 + 1];
        const float va = values[(size_t)r * D_ + lane];
        const float vb = values[(size_t)r * D_ + 64 + lane];
        // stride-1 across lanes -> 2 lanes/bank, conflict-free
        atomicAdd(&lmeans[i0 * D_ + lane],      ks0 * va);
        atomicAdd(&lmeans[i0 * D_ + 64 + lane], ks0 * vb);
        atomicAdd(&lmeans[i1 * D_ + lane],      ks1 * va);
        atomicAdd(&lmeans[i1 * D_ + 64 + lane], ks1 * vb);
    }
    __syncthreads();

    float4* dst = (float4*)(partials + (size_t)blockIdx.x * PD_);
    const float4* src = (const float4*)lmeans;
    for (int i = tid; i < PD_ / 4; i += 256) dst[i] = src[i];
}

// Kernel 2: means[i] = sum_b partials[b][i]
__global__ __launch_bounds__(256) void reduce_partials(
    const float* __restrict__ partials, float* __restrict__ means, int nb)
{
    const int i = blockIdx.x * 256 + threadIdx.x;
    if (i >= PD_) return;
    float s = 0.f;
    for (int b = 0; b < nb; ++b) s += partials[(size_t)b * PD_ + i];
    means[i] = s;
}

// Kernel 3: out[r,d] = (means[i0,d] + means[i1,d]) * q[r,d]; one wave per row
__global__ __launch_bounds__(256) void emit_out(
    const int* __restrict__ idx, const float* __restrict__ means,
    const float* __restrict__ queries, float* __restrict__ out)
{
    const int tid  = threadIdx.x;
    const int lane = tid & 63;
    const int wave = tid >> 6;
    const int r = blockIdx.x * 4 + wave;
    if (r >= BS_) return;
    const int i0 = idx[r * 2 + 0];
    const int i1 = idx[r * 2 + 1];
    const float ma = means[i0 * D_ + lane]      + means[i1 * D_ + lane];
    const float mb = means[i0 * D_ + 64 + lane] + means[i1 * D_ + 64 + lane];
    const float qa = queries[(size_t)r * D_ + lane];
    const float qb = queries[(size_t)r * D_ + 64 + lane];
    out[(size_t)r * D_ + lane]      = ma * qa;
    out[(size_t)r * D_ + 64 + lane] = mb * qb;
}

extern "C" void kernel_launch(void* const* d_in, const int* in_sizes, int n_in,
                              void* d_out, int out_size, void* d_ws, size_t ws_size,
                              hipStream_t stream) {
    const int*   idx     = (const int*)d_in[0];    // [B,S,K] int32
    const float* keys    = (const float*)d_in[1];  // [B,S,K,C] fp32
    const float* values  = (const float*)d_in[2];  // [B,S,D]  fp32
    const float* queries = (const float*)d_in[3];  // [B,S,D]  fp32
    float* out = (float*)d_out;
    float* ws = (float*)d_ws;

    // ws layout: [nb partial tables of PD_ floats][1 final means table]
    size_t slots = ws_size / (PD_ * sizeof(float));
    int nb = (int)slots - 1;
    if (nb > 128) nb = 128;
    if (nb < 1)   nb = 1;
    float* partials = ws;
    float* means    = ws + (size_t)nb * PD_;
    const int rowsPerBlk = (BS_ + nb - 1) / nb;

    scatter_partials<<<nb, 256, 0, stream>>>(idx, keys, values, partials, rowsPerBlk);
    reduce_partials<<<PD_ / 256, 256, 0, stream>>>(partials, means, nb);
    emit_out<<<BS_ / 4, 256, 0, stream>>>(idx, means, queries, out);
}

// Round 3
// 105.076 us; speedup vs baseline: 1.2038x; 1.2038x over previous
//
#include <hip/hip_runtime.h>
#include <hip/hip_bf16.h>

// Problem constants (from reference): B=4,S=2048,K=2,C=32,D=128,P=128
#define P_  128
#define C_  32
#define D_  128
#define BS_ 8192          // B*S rows
#define PD_ (P_*D_)       // 16384 floats = 64 KB
#define NB_MAX 256

// Kernel 1: per-block partial means tables in LDS, written non-atomically to ws.
// One wave handles one (b,s) row: lanes 0..63 hold keys[r, i=lane>>5, c=lane&31].
// 256 blocks x 64KB LDS -> 2 blocks/CU across all 256 CUs, 8 rows/wave serial.
__global__ __launch_bounds__(256) void scatter_partials(
    const int* __restrict__ idx, const float* __restrict__ keys,
    const float* __restrict__ values, float* __restrict__ partials,
    int rowsPerBlk)
{
    __shared__ float lmeans[PD_];
    const int tid  = threadIdx.x;
    for (int i = tid; i < PD_; i += 256) lmeans[i] = 0.f;
    __syncthreads();

    const int lane = tid & 63;
    const int wave = tid >> 6;
    const int r0 = blockIdx.x * rowsPerBlk;
    int r1 = r0 + rowsPerBlk; if (r1 > BS_) r1 = BS_;

    for (int r = r0 + wave; r < r1; r += 4) {
        // issue all loads for this row up front
        const float kv = keys[(size_t)r * 64 + lane];
        const int i0 = idx[r * 2 + 0];
        const int i1 = idx[r * 2 + 1];
        const float va = values[(size_t)r * D_ + lane];
        const float vb = values[(size_t)r * D_ + 64 + lane];
        // xor-reduce within each 32-lane half -> per-half sums everywhere
        float s = kv;
        s += __shfl_xor(s, 16);
        s += __shfl_xor(s, 8);
        s += __shfl_xor(s, 4);
        s += __shfl_xor(s, 2);
        s += __shfl_xor(s, 1);
        const float ks0 = __shfl(s, 0)  * (1.f / 32.f);  // mean over C for K=0
        const float ks1 = __shfl(s, 32) * (1.f / 32.f);  // mean over C for K=1
        // stride-1 across lanes -> 2 lanes/bank, conflict-free
        atomicAdd(&lmeans[i0 * D_ + lane],      ks0 * va);
        atomicAdd(&lmeans[i0 * D_ + 64 + lane], ks0 * vb);
        atomicAdd(&lmeans[i1 * D_ + lane],      ks1 * va);
        atomicAdd(&lmeans[i1 * D_ + 64 + lane], ks1 * vb);
    }
    __syncthreads();

    float4* dst = (float4*)(partials + (size_t)blockIdx.x * PD_);
    const float4* src = (const float4*)lmeans;
    for (int i = tid; i < PD_ / 4; i += 256) dst[i] = src[i];
}

// Kernel 2: means[i] = sum_b partials[b][i]  (64 blocks, coalesced dword lanes)
__global__ __launch_bounds__(256) void reduce_partials(
    const float* __restrict__ partials, float* __restrict__ means, int nb)
{
    const int i = blockIdx.x * 256 + threadIdx.x;
    float s = 0.f;
    #pragma unroll 8
    for (int b = 0; b < nb; ++b) s += partials[(size_t)b * PD_ + i];
    means[i] = s;
}

// Kernel 3: thread-per-float4. gid covers BS_*D_/4 = 262144 float4s.
// Lanes 0..31 of each wave share one row -> means gathers are 512B segments.
__global__ __launch_bounds__(256) void emit_out(
    const int* __restrict__ idx, const float* __restrict__ means,
    const float* __restrict__ queries, float* __restrict__ out)
{
    const int gid = blockIdx.x * 256 + threadIdx.x;   // [0, 262144)
    const int row = gid >> 5;                          // 32 float4 per row
    const int d4  = gid & 31;
    const int i0 = idx[row * 2 + 0];
    const int i1 = idx[row * 2 + 1];
    const float4 q = ((const float4*)queries)[gid];
    const float4* m4 = (const float4*)means;
    const float4 a = m4[i0 * 32 + d4];
    const float4 b = m4[i1 * 32 + d4];
    float4 o;
    o.x = (a.x + b.x) * q.x;
    o.y = (a.y + b.y) * q.y;
    o.z = (a.z + b.z) * q.z;
    o.w = (a.w + b.w) * q.w;
    ((float4*)out)[gid] = o;
}

extern "C" void kernel_launch(void* const* d_in, const int* in_sizes, int n_in,
                              void* d_out, int out_size, void* d_ws, size_t ws_size,
                              hipStream_t stream) {
    const int*   idx     = (const int*)d_in[0];    // [B,S,K] int32
    const float* keys    = (const float*)d_in[1];  // [B,S,K,C] fp32
    const float* values  = (const float*)d_in[2];  // [B,S,D]  fp32
    const float* queries = (const float*)d_in[3];  // [B,S,D]  fp32
    float* out = (float*)d_out;
    float* ws = (float*)d_ws;

    // ws layout: [nb partial tables of PD_ floats][1 final means table]
    size_t slots = ws_size / (PD_ * sizeof(float));
    int nb = (int)slots - 1;
    if (nb > NB_MAX) nb = NB_MAX;
    if (nb < 1)      nb = 1;
    float* partials = ws;
    float* means    = ws + (size_t)nb * PD_;
    const int rowsPerBlk = (BS_ + nb - 1) / nb;

    scatter_partials<<<nb, 256, 0, stream>>>(idx, keys, values, partials, rowsPerBlk);
    reduce_partials<<<PD_ / 256, 256, 0, stream>>>(partials, means, nb);
    emit_out<<<(BS_ * D_ / 4) / 256, 256, 0, stream>>>(idx, means, queries, out);
}

// Round 4
// 88.411 us; speedup vs baseline: 1.4307x; 1.1885x over previous
//
#include <hip/hip_runtime.h>
#include <hip/hip_bf16.h>

// Problem constants (from reference): B=4,S=2048,K=2,C=32,D=128,P=128
#define P_  128
#define C_  32
#define D_  128
#define BS_ 8192          // B*S rows
#define PD_ (P_*D_)       // 16384 floats = 64 KB
#define NB_ 256           // privatized partial tables (= K1 grid)

// Kernel 1: per-block partial means tables in LDS -> ws (non-atomic writeout).
// 512 threads = 8 waves; each wave owns rows r0+wave+8*j, j=0..3, fully
// prefetched (16 outstanding global loads) so the 4 shuffle->LDS-atomic
// chains overlap instead of serializing.
__global__ __launch_bounds__(512) void scatter_partials(
    const int* __restrict__ idx, const float* __restrict__ keys,
    const float* __restrict__ values, float* __restrict__ partials)
{
    __shared__ float lmeans[PD_];
    float4* lm4 = (float4*)lmeans;
    const int tid = threadIdx.x;
    for (int i = tid; i < PD_ / 4; i += 512) lm4[i] = float4{0.f, 0.f, 0.f, 0.f};
    __syncthreads();

    const int lane = tid & 63;
    const int wave = tid >> 6;                 // 0..7
    const int rbase = blockIdx.x * 32 + wave;  // rows: rbase + 8*j

    float kv[4], va[4], vb[4];
    int2  ii[4];
    #pragma unroll
    for (int j = 0; j < 4; ++j) {
        const int r = rbase + 8 * j;
        kv[j] = keys[(size_t)r * 64 + lane];          // [K=2,C=32] flat
        ii[j] = ((const int2*)idx)[r];                // both partition ids
        va[j] = values[(size_t)r * D_ + lane];
        vb[j] = values[(size_t)r * D_ + 64 + lane];
    }

    #pragma unroll
    for (int j = 0; j < 4; ++j) {
        float s = kv[j];
        s += __shfl_xor(s, 16);   // reduce within each 32-lane half
        s += __shfl_xor(s, 8);
        s += __shfl_xor(s, 4);
        s += __shfl_xor(s, 2);
        s += __shfl_xor(s, 1);
        const float ks0 = __shfl(s, 0)  * (1.f / 32.f);  // mean_c keys[r,0,:]
        const float ks1 = __shfl(s, 32) * (1.f / 32.f);  // mean_c keys[r,1,:]
        // stride-1 across lanes -> 2 lanes/bank, conflict-free
        atomicAdd(&lmeans[ii[j].x * D_ + lane],      ks0 * va[j]);
        atomicAdd(&lmeans[ii[j].x * D_ + 64 + lane], ks0 * vb[j]);
        atomicAdd(&lmeans[ii[j].y * D_ + lane],      ks1 * va[j]);
        atomicAdd(&lmeans[ii[j].y * D_ + 64 + lane], ks1 * vb[j]);
    }
    __syncthreads();

    float4* dst = (float4*)(partials + (size_t)blockIdx.x * PD_);
    for (int i = tid; i < PD_ / 4; i += 512) dst[i] = lm4[i];
}

// Kernel 2: means[e] = sum_b partials[b][e]. 256 blocks x 256 threads;
// block owns 64 elements, the 4 waves split the b-range (64 tables each),
// cross-wave combine through LDS. Every CU gets a block.
__global__ __launch_bounds__(256) void reduce_partials(
    const float* __restrict__ partials, float* __restrict__ means)
{
    __shared__ float red[4][64];
    const int t  = threadIdx.x;
    const int el = t & 63;                  // element within block's chunk
    const int g  = t >> 6;                  // b-group 0..3
    const int e  = blockIdx.x * 64 + el;    // global element 0..16383
    float s = 0.f;
    #pragma unroll 8
    for (int j = 0; j < 64; ++j)
        s += partials[(size_t)(g * 64 + j) * PD_ + e];
    red[g][el] = s;
    __syncthreads();
    if (t < 64)
        means[blockIdx.x * 64 + t] = red[0][t] + red[1][t] + red[2][t] + red[3][t];
}

// Kernel 3: thread-per-float4. gid covers BS_*D_/4 = 262144 float4s.
// 32 consecutive lanes share one row -> means gathers are 512B segments.
__global__ __launch_bounds__(256) void emit_out(
    const int* __restrict__ idx, const float* __restrict__ means,
    const float* __restrict__ queries, float* __restrict__ out)
{
    const int gid = blockIdx.x * 256 + threadIdx.x;   // [0, 262144)
    const int row = gid >> 5;                          // 32 float4 per row
    const int d4  = gid & 31;
    const int2 ii = ((const int2*)idx)[row];
    const float4 q = ((const float4*)queries)[gid];
    const float4* m4 = (const float4*)means;
    const float4 a = m4[ii.x * 32 + d4];
    const float4 b = m4[ii.y * 32 + d4];
    float4 o;
    o.x = (a.x + b.x) * q.x;
    o.y = (a.y + b.y) * q.y;
    o.z = (a.z + b.z) * q.z;
    o.w = (a.w + b.w) * q.w;
    ((float4*)out)[gid] = o;
}

extern "C" void kernel_launch(void* const* d_in, const int* in_sizes, int n_in,
                              void* d_out, int out_size, void* d_ws, size_t ws_size,
                              hipStream_t stream) {
    const int*   idx     = (const int*)d_in[0];    // [B,S,K] int32
    const float* keys    = (const float*)d_in[1];  // [B,S,K,C] fp32
    const float* values  = (const float*)d_in[2];  // [B,S,D]  fp32
    const float* queries = (const float*)d_in[3];  // [B,S,D]  fp32
    float* out = (float*)d_out;
    float* ws  = (float*)d_ws;

    // ws layout: [NB_ partial tables of PD_ floats][1 final means table]
    // needs (NB_+1)*64KB = 16.1 MB; harness ws is 256 MiB (per fill size).
    float* partials = ws;
    float* means    = ws + (size_t)NB_ * PD_;

    scatter_partials<<<NB_, 512, 0, stream>>>(idx, keys, values, partials);
    reduce_partials<<<PD_ / 64, 256, 0, stream>>>(partials, means);
    emit_out<<<(BS_ * D_ / 4) / 256, 256, 0, stream>>>(idx, means, queries, out);
}